// Round 11
// baseline (197.907 us; speedup 1.0000x reference)
//
#include <hip/hip_runtime.h>

#define B_TOTAL 2048
#define CAST    128
#define HDIM    256
#define INDIM   256
#define BM      8
#define GRU_BLOCKS (B_TOTAL / BM)     // 256
#define ROW_F4     (CAST * HDIM / 4)  // 8192 float4 per batch row

typedef float fx4 __attribute__((ext_vector_type(4)));

// ---------------- prep: rowaid/rowstop tables + weight transpose ----------------
// blocks 0..7: rowaid[row]=clamped actor id (batch_idxs covers all rows),
//              rowstop flags. blocks 8..391: pack weights as
// wt[((k4*3 + gate)*256 + h)*4 + j] = w[(gate*256 + h)*256 + k4*4 + j]
__global__ __launch_bounds__(256) void k_prep(
    const int* __restrict__ batch_idxs, const int* __restrict__ actor_ids,
    const int* __restrict__ story_stop, int n_stop,
    const float* __restrict__ w_ih, const float* __restrict__ w_hh,
    int* rowaid, int* rowstop, float* wtI, float* wtH) {
    const int t = threadIdx.x;
    if (blockIdx.x < 8) {
        int g = blockIdx.x * 256 + t;
        int row = batch_idxs[g];
        int a = actor_ids[row];
        a = a < 0 ? 0 : (a > CAST - 1 ? CAST - 1 : a);
        rowaid[row] = a;
        if (g < n_stop) rowstop[story_stop[g]] = 1;
    } else {
        int id  = blockIdx.x - 8;          // 0..383
        int mat = id / 192;                // 0: w_ih, 1: w_hh
        int rem = id % 192;
        int g   = rem / 64;
        int k4  = rem % 64;
        const float* w = mat ? w_hh : w_ih;
        float*      wt = mat ? wtH  : wtI;
        float4 wv = *(const float4*)(w + ((size_t)(g * HDIM + t) * INDIM + k4 * 4));
        *(float4*)(wt + ((size_t)((k4 * 3 + g) * HDIM + t)) * 4) = wv;
    }
}

// ---------------- fused GRU + state copy (reverse row order) ----------------
// blocks [0, GRU_BLOCKS): GRU on BM rows each.
// blocks [GRU_BLOCKS, +B_TOTAL): copy one batch row each, rows processed in
//   DESCENDING address order. Temporal loads AND temporal stores (NT-store
//   slow-path theory: all fast write paths on this chip use normal stores).
__global__ __launch_bounds__(256) void k_main(
    const float* __restrict__ x, const int* __restrict__ batch_idxs,
    const int* __restrict__ actor_ids, const float* __restrict__ state,
    const float* __restrict__ wtI, const float* __restrict__ wtH,
    const float* __restrict__ b_ih, const float* __restrict__ b_hh,
    const int* __restrict__ rowaid, const int* __restrict__ rowstop,
    float* __restrict__ out_sel, float* __restrict__ out_state) {
    __shared__ float xs[BM][INDIM];
    __shared__ float ss[BM][HDIM];
    const int h = threadIdx.x;

    if (blockIdx.x < GRU_BLOCKS) {
        const int b0 = blockIdx.x * BM;
        #pragma unroll
        for (int r = 0; r < BM; ++r) {
            int g  = b0 + r;
            int bi = batch_idxs[g];
            int a  = actor_ids[bi];
            a = a < 0 ? 0 : (a > CAST - 1 ? CAST - 1 : a);
            xs[r][h] = x[(size_t)g * INDIM + h];
            ss[r][h] = state[((size_t)bi * CAST + a) * HDIM + h];
        }
        __syncthreads();

        float air[BM], aiz[BM], ain[BM], ahr[BM], ahz[BM], ahn[BM];
        #pragma unroll
        for (int r = 0; r < BM; ++r) { air[r]=0.f; aiz[r]=0.f; ain[r]=0.f; ahr[r]=0.f; ahz[r]=0.f; ahn[r]=0.f; }

        const float4* __restrict__ wtI4 = (const float4*)wtI;
        const float4* __restrict__ wtH4 = (const float4*)wtH;

        for (int k4 = 0; k4 < INDIM / 4; ++k4) {
            float4 wir = wtI4[(k4 * 3 + 0) * HDIM + h];
            float4 wiz = wtI4[(k4 * 3 + 1) * HDIM + h];
            float4 win = wtI4[(k4 * 3 + 2) * HDIM + h];
            float4 whr = wtH4[(k4 * 3 + 0) * HDIM + h];
            float4 whz = wtH4[(k4 * 3 + 1) * HDIM + h];
            float4 whn = wtH4[(k4 * 3 + 2) * HDIM + h];
            #pragma unroll
            for (int r = 0; r < BM; ++r) {
                float4 xv = *(const float4*)(&xs[r][k4 * 4]);
                float4 sv = *(const float4*)(&ss[r][k4 * 4]);
                air[r] = fmaf(xv.w, wir.w, fmaf(xv.z, wir.z, fmaf(xv.y, wir.y, fmaf(xv.x, wir.x, air[r]))));
                aiz[r] = fmaf(xv.w, wiz.w, fmaf(xv.z, wiz.z, fmaf(xv.y, wiz.y, fmaf(xv.x, wiz.x, aiz[r]))));
                ain[r] = fmaf(xv.w, win.w, fmaf(xv.z, win.z, fmaf(xv.y, win.y, fmaf(xv.x, win.x, ain[r]))));
                ahr[r] = fmaf(sv.w, whr.w, fmaf(sv.z, whr.z, fmaf(sv.y, whr.y, fmaf(sv.x, whr.x, ahr[r]))));
                ahz[r] = fmaf(sv.w, whz.w, fmaf(sv.z, whz.z, fmaf(sv.y, whz.y, fmaf(sv.x, whz.x, ahz[r]))));
                ahn[r] = fmaf(sv.w, whn.w, fmaf(sv.z, whn.z, fmaf(sv.y, whn.y, fmaf(sv.x, whn.x, ahn[r]))));
            }
        }

        const float bir = b_ih[h], biz = b_ih[HDIM + h], bin = b_ih[2 * HDIM + h];
        const float bhr = b_hh[h], bhz = b_hh[HDIM + h], bhn = b_hh[2 * HDIM + h];

        #pragma unroll
        for (int r = 0; r < BM; ++r) {
            int g  = b0 + r;
            int bi = batch_idxs[g];
            int a  = actor_ids[bi];
            a = a < 0 ? 0 : (a > CAST - 1 ? CAST - 1 : a);
            float ir = air[r] + bir, iz = aiz[r] + biz, inn = ain[r] + bin;
            float hr = ahr[r] + bhr, hz = ahz[r] + bhz, hn = ahn[r] + bhn;
            float rr = 1.f / (1.f + __expf(-(ir + hr)));
            float zz = 1.f / (1.f + __expf(-(iz + hz)));
            float nn = tanhf(inn + rr * hn);
            float val = (1.f - zz) * nn + zz * ss[r][h];
            out_sel[(size_t)g * HDIM + h] = val;
            if (!rowstop[bi]) out_state[((size_t)bi * CAST + a) * HDIM + h] = val;
        }
    } else {
        // Reverse order: earliest-dispatched copy blocks take the HIGHEST rows.
        const int  b = B_TOTAL - 1 - (blockIdx.x - GRU_BLOCKS);
        const int  t = threadIdx.x;
        const long base = (long)b * ROW_F4;
        fx4* __restrict__ dp = (fx4*)out_state + base + t;

        if (rowstop[b]) {
            const fx4 z = (fx4)(0.f);
            #pragma unroll
            for (int j = 0; j < 32; ++j)
                dp[j * 256] = z;                          // temporal store
            return;
        }

        const fx4* __restrict__ sp = (const fx4*)state + base + t;
        // slot c covered at iteration j by c = j*4 + (t>>6): wave-scalar skip.
        const int aid = __builtin_amdgcn_readfirstlane(rowaid[b]);
        const int w   = __builtin_amdgcn_readfirstlane(t >> 6);
        const int jskip = ((aid & 3) == w) ? (aid >> 2) : -1;

        #pragma unroll
        for (int g2 = 0; g2 < 2; ++g2) {
            fx4 d[16];
            #pragma unroll
            for (int i = 0; i < 16; ++i)
                d[i] = sp[(g2 * 16 + i) * 256];          // temporal load
            #pragma unroll
            for (int i = 0; i < 16; ++i) {
                if (g2 * 16 + i != jskip)
                    dp[(g2 * 16 + i) * 256] = d[i];      // temporal store
            }
        }
    }
}

extern "C" void kernel_launch(void* const* d_in, const int* in_sizes, int n_in,
                              void* d_out, int out_size, void* d_ws, size_t ws_size,
                              hipStream_t stream) {
    const float* x          = (const float*)d_in[0];
    const int*   batch_idxs = (const int*)d_in[1];
    const int*   actor_ids  = (const int*)d_in[2];
    const int*   story_stop = (const int*)d_in[3];
    const float* state      = (const float*)d_in[4];
    const float* w_ih       = (const float*)d_in[5];
    const float* w_hh       = (const float*)d_in[6];
    const float* b_ih       = (const float*)d_in[7];
    const float* b_hh       = (const float*)d_in[8];
    const int    n_stop     = in_sizes[3];

    float* out_sel   = (float*)d_out;
    float* out_state = out_sel + (size_t)B_TOTAL * HDIM;

    int*   rowaid  = (int*)d_ws;
    int*   rowstop = rowaid + B_TOTAL;
    float* wtI     = (float*)((char*)d_ws + 16384);
    float* wtH     = wtI + (size_t)3 * HDIM * INDIM;

    hipMemsetAsync(rowstop, 0, B_TOTAL * sizeof(int), stream);
    k_prep<<<8 + 384, 256, 0, stream>>>(batch_idxs, actor_ids, story_stop, n_stop,
                                        w_ih, w_hh, rowaid, rowstop, wtI, wtH);
    k_main<<<GRU_BLOCKS + B_TOTAL, 256, 0, stream>>>(
        x, batch_idxs, actor_ids, state, wtI, wtH, b_ih, b_hh,
        rowaid, rowstop, out_sel, out_state);
}

// Round 12
// 140.163 us; speedup vs baseline: 1.4120x; 1.4120x over previous
//
#include <hip/hip_runtime.h>

#define B_TOTAL 2048
#define CAST    128
#define HDIM    256
#define INDIM   256
#define BM      8
#define GRU_BLOCKS (B_TOTAL / BM)     // 256
#define ROW_F4     (CAST * HDIM / 4)  // 8192 float4 per batch row

typedef float fx4 __attribute__((ext_vector_type(4)));

// System-scope non-temporal 16B store: bypass/no-allocate at all cache levels.
#define ST16(P, V) \
  asm volatile("global_store_dwordx4 %0, %1, off sc0 sc1 nt" \
               :: "v"((void*)(P)), "v"(V) : "memory")

// ---------------- prep: rowaid/rowstop tables + weight transpose ----------------
// blocks 0..7: rowaid[row] = clamped actor id (batch_idxs covers all rows).
// block 0 additionally: rowstop[] via LDS bitmap (no memset needed, race-free).
// blocks 8..391: wt[((k4*3+gate)*256+h)*4+j] = w[(gate*256+h)*256+k4*4+j]
__global__ __launch_bounds__(256) void k_prep(
    const int* __restrict__ batch_idxs, const int* __restrict__ actor_ids,
    const int* __restrict__ story_stop, int n_stop,
    const float* __restrict__ w_ih, const float* __restrict__ w_hh,
    int* rowaid, int* rowstop, float* wtI, float* wtH) {
    const int t = threadIdx.x;
    if (blockIdx.x < 8) {
        int g = blockIdx.x * 256 + t;
        int row = batch_idxs[g];
        int a = actor_ids[row];
        a = a < 0 ? 0 : (a > CAST - 1 ? CAST - 1 : a);
        rowaid[row] = a;
        if (blockIdx.x == 0) {
            __shared__ unsigned bmp[B_TOTAL / 32];     // 64 words
            if (t < B_TOTAL / 32) bmp[t] = 0u;
            __syncthreads();
            if (t < n_stop) {
                int r = story_stop[t];
                atomicOr(&bmp[r >> 5], 1u << (r & 31));
            }
            __syncthreads();
            #pragma unroll
            for (int i = 0; i < B_TOTAL / 256; ++i) {
                int r = t * (B_TOTAL / 256) + i;
                rowstop[r] = (bmp[r >> 5] >> (r & 31)) & 1;
            }
        }
    } else {
        int id  = blockIdx.x - 8;          // 0..383
        int mat = id / 192;                // 0: w_ih, 1: w_hh
        int rem = id % 192;
        int g   = rem / 64;
        int k4  = rem % 64;
        const float* w = mat ? w_hh : w_ih;
        float*      wt = mat ? wtH  : wtI;
        float4 wv = *(const float4*)(w + ((size_t)(g * HDIM + t) * INDIM + k4 * 4));
        *(float4*)(wt + ((size_t)((k4 * 3 + g) * HDIM + t)) * 4) = wv;
    }
}

// ---------------- fused GRU + state copy (reverse row order) ----------------
// blocks [0, GRU_BLOCKS): GRU on BM rows each.
// blocks [GRU_BLOCKS, +B_TOTAL): copy one batch row each, rows in DESCENDING
//   address order. Temporal loads (state retention in MALL); system-scope NT
//   stores (sc0 sc1 nt: keep the 264 MB write stream out of the MALL).
__global__ __launch_bounds__(256) void k_main(
    const float* __restrict__ x, const int* __restrict__ batch_idxs,
    const int* __restrict__ actor_ids, const float* __restrict__ state,
    const float* __restrict__ wtI, const float* __restrict__ wtH,
    const float* __restrict__ b_ih, const float* __restrict__ b_hh,
    const int* __restrict__ rowaid, const int* __restrict__ rowstop,
    float* __restrict__ out_sel, float* __restrict__ out_state) {
    __shared__ float xs[BM][INDIM];
    __shared__ float ss[BM][HDIM];
    const int h = threadIdx.x;

    if (blockIdx.x < GRU_BLOCKS) {
        const int b0 = blockIdx.x * BM;
        #pragma unroll
        for (int r = 0; r < BM; ++r) {
            int g  = b0 + r;
            int bi = batch_idxs[g];
            int a  = actor_ids[bi];
            a = a < 0 ? 0 : (a > CAST - 1 ? CAST - 1 : a);
            xs[r][h] = x[(size_t)g * INDIM + h];
            ss[r][h] = state[((size_t)bi * CAST + a) * HDIM + h];
        }
        __syncthreads();

        float air[BM], aiz[BM], ain[BM], ahr[BM], ahz[BM], ahn[BM];
        #pragma unroll
        for (int r = 0; r < BM; ++r) { air[r]=0.f; aiz[r]=0.f; ain[r]=0.f; ahr[r]=0.f; ahz[r]=0.f; ahn[r]=0.f; }

        const float4* __restrict__ wtI4 = (const float4*)wtI;
        const float4* __restrict__ wtH4 = (const float4*)wtH;

        for (int k4 = 0; k4 < INDIM / 4; ++k4) {
            float4 wir = wtI4[(k4 * 3 + 0) * HDIM + h];
            float4 wiz = wtI4[(k4 * 3 + 1) * HDIM + h];
            float4 win = wtI4[(k4 * 3 + 2) * HDIM + h];
            float4 whr = wtH4[(k4 * 3 + 0) * HDIM + h];
            float4 whz = wtH4[(k4 * 3 + 1) * HDIM + h];
            float4 whn = wtH4[(k4 * 3 + 2) * HDIM + h];
            #pragma unroll
            for (int r = 0; r < BM; ++r) {
                float4 xv = *(const float4*)(&xs[r][k4 * 4]);
                float4 sv = *(const float4*)(&ss[r][k4 * 4]);
                air[r] = fmaf(xv.w, wir.w, fmaf(xv.z, wir.z, fmaf(xv.y, wir.y, fmaf(xv.x, wir.x, air[r]))));
                aiz[r] = fmaf(xv.w, wiz.w, fmaf(xv.z, wiz.z, fmaf(xv.y, wiz.y, fmaf(xv.x, wiz.x, aiz[r]))));
                ain[r] = fmaf(xv.w, win.w, fmaf(xv.z, win.z, fmaf(xv.y, win.y, fmaf(xv.x, win.x, ain[r]))));
                ahr[r] = fmaf(sv.w, whr.w, fmaf(sv.z, whr.z, fmaf(sv.y, whr.y, fmaf(sv.x, whr.x, ahr[r]))));
                ahz[r] = fmaf(sv.w, whz.w, fmaf(sv.z, whz.z, fmaf(sv.y, whz.y, fmaf(sv.x, whz.x, ahz[r]))));
                ahn[r] = fmaf(sv.w, whn.w, fmaf(sv.z, whn.z, fmaf(sv.y, whn.y, fmaf(sv.x, whn.x, ahn[r]))));
            }
        }

        const float bir = b_ih[h], biz = b_ih[HDIM + h], bin = b_ih[2 * HDIM + h];
        const float bhr = b_hh[h], bhz = b_hh[HDIM + h], bhn = b_hh[2 * HDIM + h];

        #pragma unroll
        for (int r = 0; r < BM; ++r) {
            int g  = b0 + r;
            int bi = batch_idxs[g];
            int a  = actor_ids[bi];
            a = a < 0 ? 0 : (a > CAST - 1 ? CAST - 1 : a);
            float ir = air[r] + bir, iz = aiz[r] + biz, inn = ain[r] + bin;
            float hr = ahr[r] + bhr, hz = ahz[r] + bhz, hn = ahn[r] + bhn;
            float rr = 1.f / (1.f + __expf(-(ir + hr)));
            float zz = 1.f / (1.f + __expf(-(iz + hz)));
            float nn = tanhf(inn + rr * hn);
            float val = (1.f - zz) * nn + zz * ss[r][h];
            out_sel[(size_t)g * HDIM + h] = val;
            if (!rowstop[bi]) out_state[((size_t)bi * CAST + a) * HDIM + h] = val;
        }
    } else {
        // Reverse order: earliest-dispatched copy blocks take the HIGHEST rows.
        const int  b = B_TOTAL - 1 - (blockIdx.x - GRU_BLOCKS);
        const int  t = threadIdx.x;
        const long base = (long)b * ROW_F4;
        fx4* __restrict__ dp = (fx4*)out_state + base + t;

        if (rowstop[b]) {
            const fx4 z = (fx4)(0.f);
            #pragma unroll
            for (int j = 0; j < 32; ++j)
                ST16(dp + j * 256, z);
            return;
        }

        const fx4* __restrict__ sp = (const fx4*)state + base + t;
        // slot c covered at iteration j by c = j*4 + (t>>6): wave-scalar skip.
        const int aid = __builtin_amdgcn_readfirstlane(rowaid[b]);
        const int w   = __builtin_amdgcn_readfirstlane(t >> 6);
        const int jskip = ((aid & 3) == w) ? (aid >> 2) : -1;

        #pragma unroll
        for (int g2 = 0; g2 < 2; ++g2) {
            fx4 d[16];
            #pragma unroll
            for (int i = 0; i < 16; ++i)
                d[i] = sp[(g2 * 16 + i) * 256];          // temporal load
            #pragma unroll
            for (int i = 0; i < 16; ++i) {
                if (g2 * 16 + i != jskip)
                    ST16(dp + (g2 * 16 + i) * 256, d[i]);
            }
        }
    }
}

extern "C" void kernel_launch(void* const* d_in, const int* in_sizes, int n_in,
                              void* d_out, int out_size, void* d_ws, size_t ws_size,
                              hipStream_t stream) {
    const float* x          = (const float*)d_in[0];
    const int*   batch_idxs = (const int*)d_in[1];
    const int*   actor_ids  = (const int*)d_in[2];
    const int*   story_stop = (const int*)d_in[3];
    const float* state      = (const float*)d_in[4];
    const float* w_ih       = (const float*)d_in[5];
    const float* w_hh       = (const float*)d_in[6];
    const float* b_ih       = (const float*)d_in[7];
    const float* b_hh       = (const float*)d_in[8];
    const int    n_stop     = in_sizes[3];

    float* out_sel   = (float*)d_out;
    float* out_state = out_sel + (size_t)B_TOTAL * HDIM;

    int*   rowaid  = (int*)d_ws;
    int*   rowstop = rowaid + B_TOTAL;
    float* wtI     = (float*)((char*)d_ws + 16384);
    float* wtH     = wtI + (size_t)3 * HDIM * INDIM;

    k_prep<<<8 + 384, 256, 0, stream>>>(batch_idxs, actor_ids, story_stop, n_stop,
                                        w_ih, w_hh, rowaid, rowstop, wtI, wtH);
    k_main<<<GRU_BLOCKS + B_TOTAL, 256, 0, stream>>>(
        x, batch_idxs, actor_ids, state, wtI, wtH, b_ih, b_hh,
        rowaid, rowstop, out_sel, out_state);
}